// Round 1
// baseline (229.351 us; speedup 1.0000x reference)
//
#include <hip/hip_runtime.h>
#include <math.h>

// Problem constants (B=4, N=2048, D=1024, DL=64, DK=128, DC=8)
#define BB_ 4
#define NN_ 2048
#define DD_ 1024
#define DLL_ 64
#define DKK_ 128
#define DCC_ 8

// Workspace layout (float offsets)
constexpr int AV_OFF   = 0;        // B*9*1024  = 36864   av[b][j][d]
constexpr int SC_OFF   = 36864;    // B*16      = 64      [inv_tau, screen, czq0..7]
constexpr int WZ_OFF   = 36928;    // B*N*8     = 65536   Wd . z_k
constexpr int DIST_OFF = 102464;   // B*N       = 8192
constexpr int S_OFF    = 110656;   // B*N       = 8192    raw scores
constexpr int AEXP_OFF = 118848;   // B*N       = 8192    screening exponent
constexpr int W_OFF    = 127040;   // B*N       = 8192    final weights
constexpr int XBAR_OFF = 135232;   // B*1024    = 4096
constexpr int QG_OFF   = 139328;   // B*128     = 512     gamma quadratic term
constexpr int BST_OFF  = 139840;   // 8*128*128 = 131072  bsT[r][j][i] = bs[r][i][j]
constexpr int QS_OFF   = 270912;   // B*128     = 512
constexpr int US_OFF   = 271424;   // B*8*128   = 4096
constexpr int WS_FLOATS = 275520;

__device__ __forceinline__ float wave_sum(float v) {
#pragma unroll
  for (int off = 32; off > 0; off >>= 1) v += __shfl_xor(v, off, 64);
  return v;
}

// ---------------------------------------------------------------------------
// K_init: blocks [0,128)=gamma quad; [128,640)=skew basis transpose;
//         [640,672)=z-part (Wd.zk, dist); 672=scalars+czq; [673,677)=zero xbar
// ---------------------------------------------------------------------------
__global__ __launch_bounds__(256) void k_init(
    const float* __restrict__ zq_g, const float* __restrict__ z_keys,
    const float* __restrict__ Wd,   const float* __restrict__ bb,
    const float* __restrict__ be,   const float* __restrict__ bo,
    const float* __restrict__ G,    const float* __restrict__ lsig,
    float* __restrict__ ws) {
  const int tid = threadIdx.x;
  const int blk = blockIdx.x;

  if (blk < 128) {
    // qg[b, a=blk] = sum_ij G[a,i,j] zq[b,i] zq[b,j]
    __shared__ float szq[256];
    __shared__ float part[1024];
    __shared__ float red2[256];
    szq[tid] = zq_g[tid];
    __syncthreads();
    const int i = tid >> 2, jc = tid & 3;
    const float* Gp = G + blk * 4096 + i * 64 + jc * 16;
    float pb0 = 0, pb1 = 0, pb2 = 0, pb3 = 0;
#pragma unroll
    for (int k = 0; k < 16; ++k) {
      float g = Gp[k];
      int j = jc * 16 + k;
      pb0 += g * szq[0 * 64 + j];
      pb1 += g * szq[1 * 64 + j];
      pb2 += g * szq[2 * 64 + j];
      pb3 += g * szq[3 * 64 + j];
    }
    part[tid * 4 + 0] = pb0; part[tid * 4 + 1] = pb1;
    part[tid * 4 + 2] = pb2; part[tid * 4 + 3] = pb3;
    __syncthreads();
    if (tid < 64) {
#pragma unroll
      for (int b = 0; b < 4; ++b) {
        float s = part[(tid * 4 + 0) * 4 + b] + part[(tid * 4 + 1) * 4 + b] +
                  part[(tid * 4 + 2) * 4 + b] + part[(tid * 4 + 3) * 4 + b];
        red2[tid * 4 + b] = s * szq[b * 64 + tid];
      }
    }
    __syncthreads();
    if (tid < 4) {
      float s = 0;
      for (int i2 = 0; i2 < 64; ++i2) s += red2[i2 * 4 + tid];
      ws[QG_OFF + tid * 128 + blk] = s;
    }
  } else if (blk < 640) {
    // bsT[r, j, i] = bs[r, i, j] = 1.0*(bb[ij]-bb[ji]) + 0.5*(be..) + 0.3*(bo..)
    const int o = (blk - 128) * 256 + tid;   // [0, 131072)
    const int i = o & 127, j = (o >> 7) & 127, r = o >> 14;
    const int ij = r * 16384 + i * 128 + j;
    const int ji = r * 16384 + j * 128 + i;
    float v = 1.0f * (bb[ij] - bb[ji]) + 0.5f * (be[ij] - be[ji]) +
              0.3f * (bo[ij] - bo[ji]);
    ws[BST_OFF + ji] = v;
  } else if (blk < 672) {
    // per-position: wz[r] = Wd[r].z_k ; dist = |zq - zk|^2
    __shared__ float sWd[512];
    __shared__ float szq[256];
    sWd[tid] = Wd[tid];
    sWd[256 + tid] = Wd[256 + tid];
    szq[tid] = zq_g[tid];
    __syncthreads();
    const int bn = (blk - 640) * 256 + tid;
    const int b = bn >> 11;
    const float* zk = z_keys + (size_t)bn * 64;
    const float* zq = szq + b * 64;
    float wz[8] = {0, 0, 0, 0, 0, 0, 0, 0};
    float dist = 0;
    for (int l = 0; l < 64; ++l) {
      float z = zk[l];
      float dz = zq[l] - z;
      dist += dz * dz;
#pragma unroll
      for (int r = 0; r < 8; ++r) wz[r] += sWd[r * 64 + l] * z;
    }
#pragma unroll
    for (int r = 0; r < 8; ++r) ws[WZ_OFF + bn * 8 + r] = wz[r];
    ws[DIST_OFF + bn] = dist;
  } else if (blk == 672) {
    // per-batch scalars + czq (wave w handles batch b=w)
    __shared__ float szq[256];
    szq[tid] = zq_g[tid];
    __syncthreads();
    const int b = tid >> 6, l = tid & 63;
    float z = szq[b * 64 + l];
    float r2 = wave_sum(z * z);
    float cz[8];
#pragma unroll
    for (int r = 0; r < 8; ++r) cz[r] = wave_sum(Wd[r * 64 + l] * z);
    if (l == 0) {
      r2 = fminf(r2, 1.0f - 1e-6f);
      float lam = 2.0f / (1.0f - r2 + 1e-6f);
      ws[SC_OFF + b * 16 + 0] = lam / sqrtf(128.0f);                 // 1/tau
      ws[SC_OFF + b * 16 + 1] = expf(lsig[0]) * 0.5f * lam * lam;    // screen
#pragma unroll
      for (int r = 0; r < 8; ++r) ws[SC_OFF + b * 16 + 2 + r] = cz[r];
    }
  } else {
    const int b = blk - 673;
    for (int i = tid; i < 1024; i += 256) ws[XBAR_OFF + b * 1024 + i] = 0.0f;
  }
}

// ---------------------------------------------------------------------------
// K_pre: grid (B, 4). Each block redundantly computes q, u_r; then its d-slice
// of av[j][d]:  av[0] = W_K^T q + sum_r czq_r a_r,  av[1+r] = a_r = W_K^T u_r
// ---------------------------------------------------------------------------
__global__ __launch_bounds__(256) void k_pre(
    const float* __restrict__ xq_g, const float* __restrict__ zq_g,
    const float* __restrict__ WQ,   const float* __restrict__ WQz,
    const float* __restrict__ WK,   float* __restrict__ ws) {
  const int b = blockIdx.x, slice = blockIdx.y, tid = threadIdx.x;
  __shared__ float xqs[1024];
  __shared__ float zq[64];
  __shared__ float qs[128];
  __shared__ float part[256];
  for (int i = tid; i < 1024; i += 256) xqs[i] = xq_g[b * 1024 + i];
  if (tid < 64) zq[tid] = zq_g[b * 64 + tid];
  __syncthreads();

  // Phase B: q[a] = W_Q[a].xq + W_Qz[a].zq + qg[b,a]
  const int sub = tid >> 5, al = tid & 31;
  for (int g = 0; g < 4; ++g) {
    const int a = g * 32 + al;
    const float* wq = WQ + a * 1024 + sub * 128;
    const float* xs = xqs + sub * 128;
    float p = 0;
#pragma unroll 8
    for (int k = 0; k < 128; ++k) p += wq[k] * xs[k];
#pragma unroll
    for (int l = sub * 8; l < sub * 8 + 8; ++l) p += WQz[a * 64 + l] * zq[l];
    part[tid] = p;
    __syncthreads();
    if (tid < 32) {
      float s = 0;
#pragma unroll
      for (int h = 0; h < 8; ++h) s += part[h * 32 + tid];
      qs[g * 32 + tid] = s + ws[QG_OFF + b * 128 + g * 32 + tid];
    }
    __syncthreads();
  }

  // Phase C: u[r][j] = sum_i bsT[r,j,i] q[i]  (also spill q,u to ws for D)
  for (int o = tid; o < 1024; o += 256) {
    const int r = o >> 7, j = o & 127;
    const float* bst = ws + BST_OFF + r * 16384 + j * 128;
    float acc = 0;
#pragma unroll 4
    for (int i = 0; i < 128; ++i) acc += bst[i] * qs[i];
    ws[US_OFF + b * 1024 + o] = acc;
  }
  if (tid < 128) ws[QS_OFF + b * 128 + tid] = qs[tid];
  __syncthreads();

  // Phase D: av for d = slice*256 + tid
  const float* wsq = ws + QS_OFF + b * 128;
  const float* wsu = ws + US_OFF + b * 1024;
  const int d = slice * 256 + tid;
  float acc[9];
#pragma unroll
  for (int j = 0; j < 9; ++j) acc[j] = 0;
  for (int t4 = 0; t4 < 32; ++t4) {
    float4 qv = *(const float4*)(wsq + t4 * 4);
    float4 uv[8];
#pragma unroll
    for (int r = 0; r < 8; ++r)
      uv[r] = *(const float4*)(wsu + r * 128 + t4 * 4);
    const float* wkcol = WK + (t4 * 4) * 1024 + d;
    float wk0 = wkcol[0], wk1 = wkcol[1024], wk2 = wkcol[2048], wk3 = wkcol[3072];
    acc[0] += wk0 * qv.x + wk1 * qv.y + wk2 * qv.z + wk3 * qv.w;
#pragma unroll
    for (int r = 0; r < 8; ++r)
      acc[1 + r] += wk0 * uv[r].x + wk1 * uv[r].y + wk2 * uv[r].z + wk3 * uv[r].w;
  }
  float a0 = acc[0];
#pragma unroll
  for (int r = 0; r < 8; ++r) a0 += ws[SC_OFF + b * 16 + 2 + r] * acc[1 + r];
  float* av = ws + AV_OFF + b * 9216;
  av[d] = a0;
#pragma unroll
  for (int r = 0; r < 8; ++r) av[(1 + r) * 1024 + d] = acc[1 + r];
}

// ---------------------------------------------------------------------------
// K2: score pass. grid (128, B), 256 thr = 4 waves, each wave does 4 positions.
// s[b,n] = inv_tau * (av0.x - sum_r wz_r (av_r.x)) ; aexp = screen * dist
// ---------------------------------------------------------------------------
__global__ __launch_bounds__(256) void k2_scores(
    const float* __restrict__ x_keys, float* __restrict__ ws) {
  __shared__ __align__(16) float sav[9216];
  __shared__ float s_sc[2];
  const int tid = threadIdx.x;
  const int b = blockIdx.y;
  const float* avg = ws + AV_OFF + b * 9216;
  for (int i = tid * 4; i < 9216; i += 1024)
    *(float4*)(sav + i) = *(const float4*)(avg + i);
  if (tid < 2) s_sc[tid] = ws[SC_OFF + b * 16 + tid];
  __syncthreads();

  const int wave = tid >> 6, lane = tid & 63;
  const int nbase = blockIdx.x * 16 + wave * 4;
  const float* xb = x_keys + ((size_t)(b * 2048 + nbase)) * 1024;

  float acc[9][4];
#pragma unroll
  for (int j = 0; j < 9; ++j)
#pragma unroll
    for (int p = 0; p < 4; ++p) acc[j][p] = 0;

#pragma unroll
  for (int c = 0; c < 4; ++c) {
    const int off = c * 256 + lane * 4;
    float4 xv[4];
#pragma unroll
    for (int p = 0; p < 4; ++p)
      xv[p] = *(const float4*)(xb + p * 1024 + off);
#pragma unroll
    for (int j = 0; j < 9; ++j) {
      float4 a = *(const float4*)(sav + j * 1024 + off);
#pragma unroll
      for (int p = 0; p < 4; ++p)
        acc[j][p] += a.x * xv[p].x + a.y * xv[p].y + a.z * xv[p].z + a.w * xv[p].w;
    }
  }
#pragma unroll
  for (int j = 0; j < 9; ++j)
#pragma unroll
    for (int p = 0; p < 4; ++p) acc[j][p] = wave_sum(acc[j][p]);

  if (lane == 0) {
    const float it = s_sc[0], sc = s_sc[1];
    for (int p = 0; p < 4; ++p) {
      const int bn = b * 2048 + nbase + p;
      const float* wz = ws + WZ_OFF + bn * 8;
      float s = acc[0][p];
#pragma unroll
      for (int r = 0; r < 8; ++r) s -= wz[r] * acc[1 + r][p];
      ws[S_OFF + bn] = s * it;
      ws[AEXP_OFF + bn] = sc * ws[DIST_OFF + bn];
    }
  }
}

// ---------------------------------------------------------------------------
// K3: per-batch softmax + screening -> weights w[b,n]
// ---------------------------------------------------------------------------
__global__ __launch_bounds__(256) void k3_softmax(float* __restrict__ ws) {
  const int b = blockIdx.x, tid = threadIdx.x;
  __shared__ float red[256];
  float sv[8];
  float vmax = -1e30f;
#pragma unroll
  for (int i = 0; i < 8; ++i) {
    sv[i] = ws[S_OFF + b * 2048 + i * 256 + tid];
    vmax = fmaxf(vmax, sv[i]);
  }
  red[tid] = vmax;
  __syncthreads();
  for (int s = 128; s > 0; s >>= 1) {
    if (tid < s) red[tid] = fmaxf(red[tid], red[tid + s]);
    __syncthreads();
  }
  const float m = red[0];
  __syncthreads();
  float lsum = 0;
#pragma unroll
  for (int i = 0; i < 8; ++i) lsum += expf(sv[i] - m);
  red[tid] = lsum;
  __syncthreads();
  for (int s = 128; s > 0; s >>= 1) {
    if (tid < s) red[tid] += red[tid + s];
    __syncthreads();
  }
  const float rl = 1.0f / red[0];
#pragma unroll
  for (int i = 0; i < 8; ++i) {
    const int idx = b * 2048 + i * 256 + tid;
    ws[W_OFF + idx] = expf(sv[i] - m - ws[AEXP_OFF + idx]) * rl;
  }
}

// ---------------------------------------------------------------------------
// K4: xbar[b,d] += sum_n w[b,n] x[b,n,d].  grid (ntile=8, dslice=4, B=4)
// ---------------------------------------------------------------------------
__global__ __launch_bounds__(256) void k4_xbar(
    const float* __restrict__ x_keys, float* __restrict__ ws) {
  const int tid = threadIdx.x;
  const int nt = blockIdx.x, dsl = blockIdx.y, b = blockIdx.z;
  __shared__ float sw[256];
  const int n0 = nt * 256;
  sw[tid] = ws[W_OFF + b * 2048 + n0 + tid];
  __syncthreads();
  const int d = dsl * 256 + tid;
  const float* xb = x_keys + ((size_t)(b * 2048 + n0)) * 1024 + d;
  float a0 = 0, a1 = 0, a2 = 0, a3 = 0;
  for (int n = 0; n < 256; n += 4) {
    a0 += sw[n + 0] * xb[(size_t)(n + 0) * 1024];
    a1 += sw[n + 1] * xb[(size_t)(n + 1) * 1024];
    a2 += sw[n + 2] * xb[(size_t)(n + 2) * 1024];
    a3 += sw[n + 3] * xb[(size_t)(n + 3) * 1024];
  }
  atomicAdd(&ws[XBAR_OFF + b * 1024 + d], (a0 + a1) + (a2 + a3));
}

// ---------------------------------------------------------------------------
// K5: out[b] = W_O (W_V xbar[b]).  grid (B)
// ---------------------------------------------------------------------------
__global__ __launch_bounds__(256) void k5_out(
    const float* __restrict__ WV, const float* __restrict__ WO,
    const float* __restrict__ ws, float* __restrict__ out) {
  const int b = blockIdx.x, tid = threadIdx.x;
  __shared__ __align__(16) float sx[1024];
  __shared__ float sy[128];
  for (int i = tid; i < 1024; i += 256) sx[i] = ws[XBAR_OFF + b * 1024 + i];
  __syncthreads();
  const int wave = tid >> 6, lane = tid & 63;
  for (int dk = wave; dk < 128; dk += 4) {
    const float* wv = WV + dk * 1024 + lane * 4;
    float p = 0;
#pragma unroll
    for (int c = 0; c < 4; ++c) {
      float4 w4 = *(const float4*)(wv + c * 256);
      float4 x4 = *(const float4*)(sx + c * 256 + lane * 4);
      p += w4.x * x4.x + w4.y * x4.y + w4.z * x4.z + w4.w * x4.w;
    }
    p = wave_sum(p);
    if (lane == 0) sy[dk] = p;
  }
  __syncthreads();
  for (int d = tid; d < 1024; d += 256) {
    const float* wo = WO + d * 128;
    float accv = 0;
#pragma unroll 4
    for (int k = 0; k < 128; ++k) accv += wo[k] * sy[k];
    out[b * 1024 + d] = accv;
  }
}

// ---------------------------------------------------------------------------
extern "C" void kernel_launch(void* const* d_in, const int* in_sizes, int n_in,
                              void* d_out, int out_size, void* d_ws,
                              size_t ws_size, hipStream_t stream) {
  const float* xq  = (const float*)d_in[0];
  const float* zq  = (const float*)d_in[1];
  const float* xk  = (const float*)d_in[2];
  const float* zk  = (const float*)d_in[3];
  const float* WQ  = (const float*)d_in[4];
  const float* WQz = (const float*)d_in[5];
  const float* G   = (const float*)d_in[6];
  const float* WK  = (const float*)d_in[7];
  const float* WV  = (const float*)d_in[8];
  const float* WO  = (const float*)d_in[9];
  const float* Wd  = (const float*)d_in[10];
  const float* bb  = (const float*)d_in[11];
  const float* be  = (const float*)d_in[12];
  const float* bo  = (const float*)d_in[13];
  const float* ls  = (const float*)d_in[14];
  float* ws  = (float*)d_ws;
  float* out = (float*)d_out;
  if (ws_size < (size_t)WS_FLOATS * sizeof(float)) return;

  hipLaunchKernelGGL(k_init, dim3(677), dim3(256), 0, stream,
                     zq, zk, Wd, bb, be, bo, G, ls, ws);
  hipLaunchKernelGGL(k_pre, dim3(4, 4), dim3(256), 0, stream,
                     xq, zq, WQ, WQz, WK, ws);
  hipLaunchKernelGGL(k2_scores, dim3(128, 4), dim3(256), 0, stream, xk, ws);
  hipLaunchKernelGGL(k3_softmax, dim3(4), dim3(256), 0, stream, ws);
  hipLaunchKernelGGL(k4_xbar, dim3(8, 4, 4), dim3(256), 0, stream, xk, ws);
  hipLaunchKernelGGL(k5_out, dim3(4), dim3(256), 0, stream, WV, WO, ws, out);
}

// Round 2
// 167.977 us; speedup vs baseline: 1.3654x; 1.3654x over previous
//
#include <hip/hip_runtime.h>
#include <math.h>

// Problem constants (B=4, N=2048, D=1024, DL=64, DK=128, DC=8)

// Workspace layout (float offsets)
constexpr int AV_OFF   = 0;        // B*9*1024  = 36864   av[b][j][d]
constexpr int SC_OFF   = 36864;    // B*16      = 64      [inv_tau, screen, czq0..7]
constexpr int WZ_OFF   = 36928;    // B*N*8     = 65536   Wd . z_k
constexpr int DIST_OFF = 102464;   // B*N       = 8192
constexpr int S_OFF    = 110656;   // B*N       = 8192    raw scores
constexpr int AEXP_OFF = 118848;   // B*N       = 8192    screening exponent
constexpr int W_OFF    = 127040;   // B*N       = 8192    final weights
constexpr int XBAR_OFF = 135232;   // B*1024    = 4096
constexpr int QG_OFF   = 139328;   // B*128     = 512     gamma quadratic term
constexpr int QS_OFF   = 139840;   // B*128     = 512     q vectors
constexpr int US_OFF   = 140352;   // B*8*128   = 4096    u[b][r][j]
constexpr int Y_OFF    = 144448;   // B*128     = 512     y = WV xbar
constexpr int WS_FLOATS = 144960;

__device__ __forceinline__ float wave_sum(float v) {
#pragma unroll
  for (int off = 32; off > 0; off >>= 1) v += __shfl_xor(v, off, 64);
  return v;
}

// ---------------------------------------------------------------------------
// K_init: blocks [0,128)=gamma quad; [128,160)=z-part (Wd.zk, dist);
//         160=scalars+czq; [161,165)=zero xbar
// ---------------------------------------------------------------------------
__global__ __launch_bounds__(256) void k_init(
    const float* __restrict__ zq_g, const float* __restrict__ z_keys,
    const float* __restrict__ Wd,   const float* __restrict__ G,
    const float* __restrict__ lsig, float* __restrict__ ws) {
  const int tid = threadIdx.x;
  const int blk = blockIdx.x;

  if (blk < 128) {
    // qg[b, a=blk] = sum_ij G[a,i,j] zq[b,i] zq[b,j]
    __shared__ float szq[256];
    __shared__ float part[1024];
    __shared__ float red2[256];
    szq[tid] = zq_g[tid];
    __syncthreads();
    const int i = tid >> 2, jc = tid & 3;
    const float* Gp = G + blk * 4096 + i * 64 + jc * 16;
    float pb0 = 0, pb1 = 0, pb2 = 0, pb3 = 0;
#pragma unroll
    for (int k = 0; k < 16; ++k) {
      float g = Gp[k];
      int j = jc * 16 + k;
      pb0 += g * szq[0 * 64 + j];
      pb1 += g * szq[1 * 64 + j];
      pb2 += g * szq[2 * 64 + j];
      pb3 += g * szq[3 * 64 + j];
    }
    part[tid * 4 + 0] = pb0; part[tid * 4 + 1] = pb1;
    part[tid * 4 + 2] = pb2; part[tid * 4 + 3] = pb3;
    __syncthreads();
    if (tid < 64) {
#pragma unroll
      for (int b = 0; b < 4; ++b) {
        float s = part[(tid * 4 + 0) * 4 + b] + part[(tid * 4 + 1) * 4 + b] +
                  part[(tid * 4 + 2) * 4 + b] + part[(tid * 4 + 3) * 4 + b];
        red2[tid * 4 + b] = s * szq[b * 64 + tid];
      }
    }
    __syncthreads();
    if (tid < 4) {
      float s = 0;
      for (int i2 = 0; i2 < 64; ++i2) s += red2[i2 * 4 + tid];
      ws[QG_OFF + tid * 128 + blk] = s;
    }
  } else if (blk < 160) {
    // per-position: wz[r] = Wd[r].z_k ; dist = |zq - zk|^2
    __shared__ float sWd[512];
    __shared__ float szq[256];
    sWd[tid] = Wd[tid];
    sWd[256 + tid] = Wd[256 + tid];
    szq[tid] = zq_g[tid];
    __syncthreads();
    const int bn = (blk - 128) * 256 + tid;
    const int b = bn >> 11;
    const float* zk = z_keys + (size_t)bn * 64;
    const float* zq = szq + b * 64;
    float wz[8] = {0, 0, 0, 0, 0, 0, 0, 0};
    float dist = 0;
    for (int l = 0; l < 64; ++l) {
      float z = zk[l];
      float dz = zq[l] - z;
      dist += dz * dz;
#pragma unroll
      for (int r = 0; r < 8; ++r) wz[r] += sWd[r * 64 + l] * z;
    }
#pragma unroll
    for (int r = 0; r < 8; ++r) ws[WZ_OFF + bn * 8 + r] = wz[r];
    ws[DIST_OFF + bn] = dist;
  } else if (blk == 160) {
    // per-batch scalars + czq (wave w handles batch b=w)
    __shared__ float szq[256];
    szq[tid] = zq_g[tid];
    __syncthreads();
    const int b = tid >> 6, l = tid & 63;
    float z = szq[b * 64 + l];
    float r2 = wave_sum(z * z);
    float cz[8];
#pragma unroll
    for (int r = 0; r < 8; ++r) cz[r] = wave_sum(Wd[r * 64 + l] * z);
    if (l == 0) {
      r2 = fminf(r2, 1.0f - 1e-6f);
      float lam = 2.0f / (1.0f - r2 + 1e-6f);
      ws[SC_OFF + b * 16 + 0] = lam / sqrtf(128.0f);                 // 1/tau
      ws[SC_OFF + b * 16 + 1] = expf(lsig[0]) * 0.5f * lam * lam;    // screen
#pragma unroll
      for (int r = 0; r < 8; ++r) ws[SC_OFF + b * 16 + 2 + r] = cz[r];
    }
  } else {
    const int b = blk - 161;
    for (int i = tid; i < 1024; i += 256) ws[XBAR_OFF + b * 1024 + i] = 0.0f;
  }
}

// ---------------------------------------------------------------------------
// K_q: grid (4 b, 8 aslice). q[a] = W_Q[a].xq + W_Qz[a].zq + qg[b,a]
// 16 a per block; 16 threads per a, each covering 64 k's.
// ---------------------------------------------------------------------------
__global__ __launch_bounds__(256) void k_q(
    const float* __restrict__ xq_g, const float* __restrict__ zq_g,
    const float* __restrict__ WQ,   const float* __restrict__ WQz,
    float* __restrict__ ws) {
  const int b = blockIdx.x, as_ = blockIdx.y, tid = threadIdx.x;
  __shared__ __align__(16) float xqs[1024];
  __shared__ float zq[64];
  __shared__ float part[256];
  for (int i = tid; i < 1024; i += 256) xqs[i] = xq_g[b * 1024 + i];
  if (tid < 64) zq[tid] = zq_g[b * 64 + tid];
  __syncthreads();

  const int a_loc = tid >> 4, seg = tid & 15;
  const int a = as_ * 16 + a_loc;
  const float4* wq4 = (const float4*)(WQ + a * 1024 + seg * 64);
  const float4* xs4 = (const float4*)(xqs + seg * 64);
  float p = 0;
#pragma unroll
  for (int c = 0; c < 16; ++c) {
    float4 w = wq4[c], x = xs4[c];
    p += w.x * x.x + w.y * x.y + w.z * x.z + w.w * x.w;
  }
#pragma unroll
  for (int c = 0; c < 4; ++c)
    p += WQz[a * 64 + seg * 4 + c] * zq[seg * 4 + c];
  part[tid] = p;
  __syncthreads();
  if (tid < 16) {
    float s = 0;
#pragma unroll
    for (int h = 0; h < 16; ++h) s += part[tid * 16 + h];
    const int aa = as_ * 16 + tid;
    ws[QS_OFF + b * 128 + aa] = s + ws[QG_OFF + b * 128 + aa];
  }
}

// ---------------------------------------------------------------------------
// K_u: grid 8 (r). u[b,r,j] = sum_i skew_r[i,j] q[b,i], skew applied on the
// fly from bb/be/bo tiles staged in padded LDS (no materialized transpose).
// ---------------------------------------------------------------------------
__global__ __launch_bounds__(256) void k_u(
    const float* __restrict__ bb, const float* __restrict__ be,
    const float* __restrict__ bo, float* __restrict__ ws) {
  const int r = blockIdx.x, tid = threadIdx.x;
  __shared__ float tmp[128 * 129];   // padded tile
  __shared__ float sq[512];          // q[b][i]
  __shared__ float red[1024];        // [half][b][j]
  for (int o = tid; o < 512; o += 256) sq[o] = ws[QS_OFF + o];
  __syncthreads();

  const int j = tid & 127, half = tid >> 7;
  float acc[4] = {0, 0, 0, 0};
  const float* arrs[3] = {bb, be, bo};
  const float wgt[3] = {1.0f, 0.5f, 0.3f};

  for (int arr = 0; arr < 3; ++arr) {
    // stage 128x128 tile (row-major) into tmp with pad 129
    const float4* src = (const float4*)(arrs[arr] + r * 16384);
    for (int idx = tid; idx < 4096; idx += 256) {
      float4 v = src[idx];
      const int i = idx >> 5, col = (idx & 31) * 4;
      float* dst = tmp + i * 129 + col;
      dst[0] = v.x; dst[1] = v.y; dst[2] = v.z; dst[3] = v.w;
    }
    __syncthreads();
    const float w = wgt[arr];
    for (int ii = 0; ii < 64; ++ii) {
      const int i = half * 64 + ii;
      const float d = w * (tmp[i * 129 + j] - tmp[j * 129 + i]);
#pragma unroll
      for (int b = 0; b < 4; ++b) acc[b] += d * sq[b * 128 + i];
    }
    __syncthreads();
  }
#pragma unroll
  for (int b = 0; b < 4; ++b) red[half * 512 + b * 128 + j] = acc[b];
  __syncthreads();
  for (int o = tid; o < 512; o += 256) {
    const int b = o >> 7, jj = o & 127;
    ws[US_OFF + b * 1024 + r * 128 + jj] = red[o] + red[512 + o];
  }
}

// ---------------------------------------------------------------------------
// K_av: grid (4 b, 16 dslice). av[j][d] = sum_k QU[j][k] WK[k][d];
// av[0] += sum_r czq_r av[1+r].  64 d per block; 4 k-quarters reduced in LDS.
// ---------------------------------------------------------------------------
__global__ __launch_bounds__(256) void k_av(
    const float* __restrict__ WK, float* __restrict__ ws) {
  const int b = blockIdx.x, dbase = blockIdx.y * 64, tid = threadIdx.x;
  __shared__ float qu[1152];    // [j][k]: j=0 -> q, j=1+r -> u[r]
  __shared__ float part[2304];  // [kq][j][dloc]
  __shared__ float fin[576];    // [j][dloc]
  __shared__ float czq[8];
  for (int o = tid; o < 1152; o += 256)
    qu[o] = (o < 128) ? ws[QS_OFF + b * 128 + o]
                      : ws[US_OFF + b * 1024 + (o - 128)];
  if (tid < 8) czq[tid] = ws[SC_OFF + b * 16 + 2 + tid];
  __syncthreads();

  const int kq = tid >> 6, dloc = tid & 63;
  float acc[9];
#pragma unroll
  for (int jj = 0; jj < 9; ++jj) acc[jj] = 0;
  const float* wkp = WK + dbase + dloc;
#pragma unroll 4
  for (int k = kq * 32; k < kq * 32 + 32; ++k) {
    const float wk = wkp[k * 1024];
#pragma unroll
    for (int jj = 0; jj < 9; ++jj) acc[jj] += qu[jj * 128 + k] * wk;
  }
#pragma unroll
  for (int jj = 0; jj < 9; ++jj) part[kq * 576 + jj * 64 + dloc] = acc[jj];
  __syncthreads();
  for (int o = tid; o < 576; o += 256)
    fin[o] = part[o] + part[576 + o] + part[1152 + o] + part[1728 + o];
  __syncthreads();
  float* av = ws + AV_OFF + b * 9216;
  for (int o = tid; o < 576; o += 256) {
    const int jj = o >> 6, dl = o & 63;
    float val = fin[o];
    if (jj == 0) {
#pragma unroll
      for (int rr = 0; rr < 8; ++rr) val += czq[rr] * fin[(1 + rr) * 64 + dl];
    }
    av[jj * 1024 + dbase + dl] = val;
  }
}

// ---------------------------------------------------------------------------
// K2: score pass. grid (128, B), 256 thr = 4 waves, each wave does 4 positions.
// ---------------------------------------------------------------------------
__global__ __launch_bounds__(256) void k2_scores(
    const float* __restrict__ x_keys, float* __restrict__ ws) {
  __shared__ __align__(16) float sav[9216];
  __shared__ float s_sc[2];
  const int tid = threadIdx.x;
  const int b = blockIdx.y;
  const float* avg = ws + AV_OFF + b * 9216;
  for (int i = tid * 4; i < 9216; i += 1024)
    *(float4*)(sav + i) = *(const float4*)(avg + i);
  if (tid < 2) s_sc[tid] = ws[SC_OFF + b * 16 + tid];
  __syncthreads();

  const int wave = tid >> 6, lane = tid & 63;
  const int nbase = blockIdx.x * 16 + wave * 4;
  const float* xb = x_keys + ((size_t)(b * 2048 + nbase)) * 1024;

  float acc[9][4];
#pragma unroll
  for (int j = 0; j < 9; ++j)
#pragma unroll
    for (int p = 0; p < 4; ++p) acc[j][p] = 0;

#pragma unroll
  for (int c = 0; c < 4; ++c) {
    const int off = c * 256 + lane * 4;
    float4 xv[4];
#pragma unroll
    for (int p = 0; p < 4; ++p)
      xv[p] = *(const float4*)(xb + p * 1024 + off);
#pragma unroll
    for (int j = 0; j < 9; ++j) {
      float4 a = *(const float4*)(sav + j * 1024 + off);
#pragma unroll
      for (int p = 0; p < 4; ++p)
        acc[j][p] += a.x * xv[p].x + a.y * xv[p].y + a.z * xv[p].z + a.w * xv[p].w;
    }
  }
#pragma unroll
  for (int j = 0; j < 9; ++j)
#pragma unroll
    for (int p = 0; p < 4; ++p) acc[j][p] = wave_sum(acc[j][p]);

  if (lane == 0) {
    const float it = s_sc[0], sc = s_sc[1];
    for (int p = 0; p < 4; ++p) {
      const int bn = b * 2048 + nbase + p;
      const float* wz = ws + WZ_OFF + bn * 8;
      float s = acc[0][p];
#pragma unroll
      for (int r = 0; r < 8; ++r) s -= wz[r] * acc[1 + r][p];
      ws[S_OFF + bn] = s * it;
      ws[AEXP_OFF + bn] = sc * ws[DIST_OFF + bn];
    }
  }
}

// ---------------------------------------------------------------------------
// K3: per-batch softmax + screening -> weights w[b,n]
// ---------------------------------------------------------------------------
__global__ __launch_bounds__(256) void k3_softmax(float* __restrict__ ws) {
  const int b = blockIdx.x, tid = threadIdx.x;
  __shared__ float red[256];
  float sv[8];
  float vmax = -1e30f;
#pragma unroll
  for (int i = 0; i < 8; ++i) {
    sv[i] = ws[S_OFF + b * 2048 + i * 256 + tid];
    vmax = fmaxf(vmax, sv[i]);
  }
  red[tid] = vmax;
  __syncthreads();
  for (int s = 128; s > 0; s >>= 1) {
    if (tid < s) red[tid] = fmaxf(red[tid], red[tid + s]);
    __syncthreads();
  }
  const float m = red[0];
  __syncthreads();
  float lsum = 0;
#pragma unroll
  for (int i = 0; i < 8; ++i) lsum += expf(sv[i] - m);
  red[tid] = lsum;
  __syncthreads();
  for (int s = 128; s > 0; s >>= 1) {
    if (tid < s) red[tid] += red[tid + s];
    __syncthreads();
  }
  const float rl = 1.0f / red[0];
#pragma unroll
  for (int i = 0; i < 8; ++i) {
    const int idx = b * 2048 + i * 256 + tid;
    ws[W_OFF + idx] = expf(sv[i] - m - ws[AEXP_OFF + idx]) * rl;
  }
}

// ---------------------------------------------------------------------------
// K4: xbar[b,d] += sum_n w[b,n] x[b,n,d].  grid (ntile=8, dslice=4, B=4)
// ---------------------------------------------------------------------------
__global__ __launch_bounds__(256) void k4_xbar(
    const float* __restrict__ x_keys, float* __restrict__ ws) {
  const int tid = threadIdx.x;
  const int nt = blockIdx.x, dsl = blockIdx.y, b = blockIdx.z;
  __shared__ float sw[256];
  const int n0 = nt * 256;
  sw[tid] = ws[W_OFF + b * 2048 + n0 + tid];
  __syncthreads();
  const int d = dsl * 256 + tid;
  const float* xb = x_keys + ((size_t)(b * 2048 + n0)) * 1024 + d;
  float a0 = 0, a1 = 0, a2 = 0, a3 = 0;
  for (int n = 0; n < 256; n += 4) {
    a0 += sw[n + 0] * xb[(size_t)(n + 0) * 1024];
    a1 += sw[n + 1] * xb[(size_t)(n + 1) * 1024];
    a2 += sw[n + 2] * xb[(size_t)(n + 2) * 1024];
    a3 += sw[n + 3] * xb[(size_t)(n + 3) * 1024];
  }
  atomicAdd(&ws[XBAR_OFF + b * 1024 + d], (a0 + a1) + (a2 + a3));
}

// ---------------------------------------------------------------------------
// K5a: y[b,dk] = WV[dk].xbar[b].  grid (4 b, 8 dkslice of 16)
// ---------------------------------------------------------------------------
__global__ __launch_bounds__(256) void k5a_y(
    const float* __restrict__ WV, float* __restrict__ ws) {
  const int b = blockIdx.x, sl = blockIdx.y, tid = threadIdx.x;
  __shared__ __align__(16) float sx[1024];
  __shared__ float part[256];
  for (int i = tid; i < 1024; i += 256) sx[i] = ws[XBAR_OFF + b * 1024 + i];
  __syncthreads();
  const int dk_loc = tid >> 4, seg = tid & 15;
  const int dk = sl * 16 + dk_loc;
  const float4* wv4 = (const float4*)(WV + dk * 1024 + seg * 64);
  const float4* xs4 = (const float4*)(sx + seg * 64);
  float p = 0;
#pragma unroll
  for (int c = 0; c < 16; ++c) {
    float4 w = wv4[c], x = xs4[c];
    p += w.x * x.x + w.y * x.y + w.z * x.z + w.w * x.w;
  }
  part[tid] = p;
  __syncthreads();
  if (tid < 16) {
    float s = 0;
#pragma unroll
    for (int h = 0; h < 16; ++h) s += part[tid * 16 + h];
    ws[Y_OFF + b * 128 + sl * 16 + tid] = s;
  }
}

// ---------------------------------------------------------------------------
// K5b: out[b,d] = WO[d].y[b].  grid (4 b, 4 dslice of 256)
// ---------------------------------------------------------------------------
__global__ __launch_bounds__(256) void k5b_out(
    const float* __restrict__ WO, const float* __restrict__ ws,
    float* __restrict__ out) {
  const int b = blockIdx.x, dsl = blockIdx.y, tid = threadIdx.x;
  __shared__ float sy[128];
  if (tid < 128) sy[tid] = ws[Y_OFF + b * 128 + tid];
  __syncthreads();
  const int d = dsl * 256 + tid;
  const float4* wo4 = (const float4*)(WO + d * 128);
  float acc = 0;
#pragma unroll
  for (int c = 0; c < 32; ++c) {
    float4 w = wo4[c];
    acc += w.x * sy[c * 4 + 0] + w.y * sy[c * 4 + 1] +
           w.z * sy[c * 4 + 2] + w.w * sy[c * 4 + 3];
  }
  out[b * 1024 + d] = acc;
}

// ---------------------------------------------------------------------------
extern "C" void kernel_launch(void* const* d_in, const int* in_sizes, int n_in,
                              void* d_out, int out_size, void* d_ws,
                              size_t ws_size, hipStream_t stream) {
  const float* xq  = (const float*)d_in[0];
  const float* zq  = (const float*)d_in[1];
  const float* xk  = (const float*)d_in[2];
  const float* zk  = (const float*)d_in[3];
  const float* WQ  = (const float*)d_in[4];
  const float* WQz = (const float*)d_in[5];
  const float* G   = (const float*)d_in[6];
  const float* WK  = (const float*)d_in[7];
  const float* WV  = (const float*)d_in[8];
  const float* WO  = (const float*)d_in[9];
  const float* Wd  = (const float*)d_in[10];
  const float* bb  = (const float*)d_in[11];
  const float* be  = (const float*)d_in[12];
  const float* bo  = (const float*)d_in[13];
  const float* ls  = (const float*)d_in[14];
  float* ws  = (float*)d_ws;
  float* out = (float*)d_out;
  if (ws_size < (size_t)WS_FLOATS * sizeof(float)) return;

  hipLaunchKernelGGL(k_init, dim3(165), dim3(256), 0, stream,
                     zq, zk, Wd, G, ls, ws);
  hipLaunchKernelGGL(k_q, dim3(4, 8), dim3(256), 0, stream,
                     xq, zq, WQ, WQz, ws);
  hipLaunchKernelGGL(k_u, dim3(8), dim3(256), 0, stream, bb, be, bo, ws);
  hipLaunchKernelGGL(k_av, dim3(4, 16), dim3(256), 0, stream, WK, ws);
  hipLaunchKernelGGL(k2_scores, dim3(128, 4), dim3(256), 0, stream, xk, ws);
  hipLaunchKernelGGL(k3_softmax, dim3(4), dim3(256), 0, stream, ws);
  hipLaunchKernelGGL(k4_xbar, dim3(8, 4, 4), dim3(256), 0, stream, xk, ws);
  hipLaunchKernelGGL(k5a_y, dim3(4, 8), dim3(256), 0, stream, WV, ws);
  hipLaunchKernelGGL(k5b_out, dim3(4, 4), dim3(256), 0, stream, WO, ws, out);
}